// Round 2
// baseline (12598.852 us; speedup 1.0000x reference)
//
#include <hip/hip_runtime.h>

#define B_ 128
#define T_ 200
#define INF_ 175
#define INFP_ 192
#define H_ 1024
#define G4_ 4096
#define OUTF_ 175
#define BH3_ (3 * B_ * H_)

typedef __bf16 bf16x8 __attribute__((ext_vector_type(8)));
typedef float f32x4 __attribute__((ext_vector_type(4)));

// ---- persistent device state (avoids any dependence on ws_size) ----
__device__ __attribute__((aligned(16))) __bf16 g_Wih1p[G4_ * INFP_];
__device__ __attribute__((aligned(16))) __bf16 g_Whh1[G4_ * H_];
__device__ __attribute__((aligned(16))) __bf16 g_Wih2[G4_ * H_];
__device__ __attribute__((aligned(16))) __bf16 g_Whh2[G4_ * H_];
__device__ __attribute__((aligned(16))) __bf16 g_Wih3[G4_ * H_];
__device__ __attribute__((aligned(16))) __bf16 g_Whh3[G4_ * H_];
__device__ __attribute__((aligned(16))) __bf16 g_Wdec[OUTF_ * H_];
__device__ float g_bsum[3 * G4_];
__device__ float g_bdec[OUTF_];
__device__ __attribute__((aligned(16))) __bf16 g_h[2][BH3_];
__device__ float g_c[BH3_];
__device__ __attribute__((aligned(16))) __bf16 g_infp[B_ * INFP_];
__device__ int g_isf32;

__device__ __forceinline__ f32x4 mfma_bf16(bf16x8 a, bf16x8 b, f32x4 c) {
    return __builtin_amdgcn_mfma_f32_16x16x32_bf16(a, b, c, 0, 0, 0);
}
__device__ __forceinline__ bf16x8 ld8(const __bf16* p) {
    return *reinterpret_cast<const bf16x8*>(p);
}
__device__ __forceinline__ float sigm(float x) { return 1.f / (1.f + expf(-x)); }
__device__ __forceinline__ float rdf(const void* p, long i, int f32) {
    return f32 ? ((const float*)p)[i] : (float)((const __bf16*)p)[i];
}

// ---- dtype probe: bf16 exponent field of N(0,1) data never reaches 140;
// fp32 low-mantissa bits are ~uniform -> ~45% of words hit >=140.
__global__ void detect_k(const unsigned int* __restrict__ xw) {
    __shared__ int cnt;
    if (threadIdx.x == 0) cnt = 0;
    __syncthreads();
    unsigned int w = xw[threadIdx.x];
    int e = (w >> 7) & 0xFF;
    if (e >= 140) atomicAdd(&cnt, 1);
    __syncthreads();
    if (threadIdx.x == 0) g_isf32 = (cnt >= 16) ? 1 : 0;
}

// ---- prep: convert/copy all weights to bf16 globals, pad W_ih1, sum biases,
// zero h/c, build in_frame(0) = x_0.
__global__ void prep_k(const void* Wih1, const void* Whh1, const void* Wih2,
                       const void* Whh2, const void* Wih3, const void* Whh3,
                       const void* Wdec, const void* bih1, const void* bhh1,
                       const void* bih2, const void* bhh2, const void* bih3,
                       const void* bhh3, const void* bdec, const void* xseq) {
    const int f = g_isf32;
    const int idx = blockIdx.x * 256 + threadIdx.x;
    const int stride = gridDim.x * 256;
    for (int i = idx; i < G4_ * INFP_; i += stride) {
        int n = i / INFP_, k = i - n * INFP_;
        g_Wih1p[i] = (k < INF_) ? (__bf16)rdf(Wih1, (long)n * INF_ + k, f) : (__bf16)0.f;
    }
    for (int i = idx; i < G4_ * H_; i += stride) {
        g_Whh1[i] = (__bf16)rdf(Whh1, i, f);
        g_Wih2[i] = (__bf16)rdf(Wih2, i, f);
        g_Whh2[i] = (__bf16)rdf(Whh2, i, f);
        g_Wih3[i] = (__bf16)rdf(Wih3, i, f);
        g_Whh3[i] = (__bf16)rdf(Whh3, i, f);
    }
    for (int i = idx; i < OUTF_ * H_; i += stride) g_Wdec[i] = (__bf16)rdf(Wdec, i, f);
    for (int i = idx; i < G4_; i += stride) {
        g_bsum[i]           = rdf(bih1, i, f) + rdf(bhh1, i, f);
        g_bsum[G4_ + i]     = rdf(bih2, i, f) + rdf(bhh2, i, f);
        g_bsum[2 * G4_ + i] = rdf(bih3, i, f) + rdf(bhh3, i, f);
    }
    for (int i = idx; i < OUTF_; i += stride) g_bdec[i] = rdf(bdec, i, f);
    for (int i = idx; i < 2 * BH3_; i += stride) (&g_h[0][0])[i] = (__bf16)0.f;
    for (int i = idx; i < BH3_; i += stride) g_c[i] = 0.f;
    for (int i = idx; i < B_ * INFP_; i += stride) {
        int b = i / INFP_, k = i - b * INFP_;
        g_infp[i] = (k < INF_) ? (__bf16)rdf(xseq, (long)b * (T_ * INF_) + k, f) : (__bf16)0.f;
    }
}

// ---- cells: all 3 LSTM cells for one timestep ----
// grid = 192 blocks: layer = blockIdx>>6, 16 h-cols per block (all 4 gates),
// block = 256 thr = 4 waves; wave w owns rows [w*32, w*32+32).
__global__ __launch_bounds__(256) void cells_k(int p) {
    const int L = blockIdx.x >> 6;
    const int hc0 = (blockIdx.x & 63) << 4;
    const int lane = threadIdx.x & 63;
    const int wid = threadIdx.x >> 6;
    const int rlo = lane & 15;
    const int khi = lane >> 4;

    const __bf16* hin = g_h[p];

    const __bf16 *A0, *B0, *A1, *B1;
    int sA0, K0;
    if (L == 0)      { A0 = g_infp;          sA0 = INFP_; K0 = INFP_; B0 = g_Wih1p; A1 = hin;             B1 = g_Whh1; }
    else if (L == 1) { A0 = hin;             sA0 = H_;    K0 = H_;    B0 = g_Wih2;  A1 = hin + B_ * H_;   B1 = g_Whh2; }
    else             { A0 = hin + B_ * H_;   sA0 = H_;    K0 = H_;    B0 = g_Wih3;  A1 = hin + 2*B_*H_;   B1 = g_Whh3; }

    f32x4 acc[2][4] = {};
    const int rm0 = wid * 32 + rlo;
    const int rm1 = wid * 32 + 16 + rlo;

    for (int k = khi * 8; k < K0; k += 32) {
        bf16x8 a0 = ld8(A0 + rm0 * sA0 + k);
        bf16x8 a1 = ld8(A0 + rm1 * sA0 + k);
#pragma unroll
        for (int g = 0; g < 4; ++g) {
            bf16x8 b = ld8(B0 + (g * H_ + hc0 + rlo) * K0 + k);
            acc[0][g] = mfma_bf16(a0, b, acc[0][g]);
            acc[1][g] = mfma_bf16(a1, b, acc[1][g]);
        }
    }
    for (int k = khi * 8; k < H_; k += 32) {
        bf16x8 a0 = ld8(A1 + rm0 * H_ + k);
        bf16x8 a1 = ld8(A1 + rm1 * H_ + k);
#pragma unroll
        for (int g = 0; g < 4; ++g) {
            bf16x8 b = ld8(B1 + (g * H_ + hc0 + rlo) * H_ + k);
            acc[0][g] = mfma_bf16(a0, b, acc[0][g]);
            acc[1][g] = mfma_bf16(a1, b, acc[1][g]);
        }
    }

    float* cL = g_c + L * B_ * H_;
    __bf16* hL = g_h[p ^ 1] + L * B_ * H_;
    const float* bs = g_bsum + L * G4_;
    const int col = hc0 + rlo;
#pragma unroll
    for (int mi = 0; mi < 2; ++mi) {
#pragma unroll
        for (int j = 0; j < 4; ++j) {
            int row = wid * 32 + mi * 16 + khi * 4 + j;
            float gi = acc[mi][0][j] + bs[0 * H_ + col];
            float gf = acc[mi][1][j] + bs[1 * H_ + col];
            float gg = acc[mi][2][j] + bs[2 * H_ + col];
            float go = acc[mi][3][j] + bs[3 * H_ + col];
            float cn = sigm(gf) * cL[row * H_ + col] + sigm(gi) * tanhf(gg);
            cL[row * H_ + col] = cn;
            hL[row * H_ + col] = (__bf16)(sigm(go) * tanhf(cn));
        }
    }
}

// ---- decoder: out(t) = nh2 @ Wdec^T + bdec; writes d_out and in_frame(t+1) ----
// grid = 22 blocks = 2 m-halves x 11 n-frags (175 cols padded to 176)
__global__ __launch_bounds__(256) void dec_k(const void* __restrict__ xseq,
                                             void* __restrict__ dout,
                                             int p, int t, int gt_next) {
    const int nb = blockIdx.x % 11;
    const int mh = blockIdx.x / 11;
    const int lane = threadIdx.x & 63;
    const int wid = threadIdx.x >> 6;
    const int rlo = lane & 15, khi = lane >> 4;
    const int col = nb * 16 + rlo;
    const int colc = (col < OUTF_) ? col : (OUTF_ - 1);
    const int f = g_isf32;

    const __bf16* h2 = g_h[p ^ 1] + 2 * B_ * H_;

    f32x4 acc = {};
    const int rowA = mh * 64 + wid * 16 + rlo;
    for (int k = khi * 8; k < H_; k += 32) {
        bf16x8 a = ld8(h2 + rowA * H_ + k);
        bf16x8 b = ld8(g_Wdec + colc * H_ + k);
        acc = mfma_bf16(a, b, acc);
    }
    if (col < OUTF_) {
        float bias = g_bdec[col];
#pragma unroll
        for (int j = 0; j < 4; ++j) {
            int row = mh * 64 + wid * 16 + khi * 4 + j;
            float ov = acc[j] + bias;
            long oidx = (long)row * (T_ * OUTF_) + (long)t * OUTF_ + col;
            if (f) ((float*)dout)[oidx] = ov;
            else   ((__bf16*)dout)[oidx] = (__bf16)ov;
            if (t + 1 < T_) {
                float nxt = gt_next ? rdf(xseq, (long)row * (T_ * INF_) + (long)(t + 1) * INF_ + col, f)
                                    : ov;
                g_infp[row * INFP_ + col] = (__bf16)nxt;
            }
        }
    }
}

extern "C" void kernel_launch(void* const* d_in, const int* in_sizes, int n_in,
                              void* d_out, int out_size, void* d_ws, size_t ws_size,
                              hipStream_t stream) {
    const void* xseq = d_in[0];
    detect_k<<<1, 256, 0, stream>>>((const unsigned int*)xseq);
    prep_k<<<2048, 256, 0, stream>>>(d_in[1], d_in[2], d_in[5], d_in[6], d_in[9],
                                     d_in[10], d_in[13], d_in[3], d_in[4], d_in[7],
                                     d_in[8], d_in[11], d_in[12], d_in[14], xseq);
    for (int t = 0; t < T_; ++t) {
        int p = t & 1;
        cells_k<<<192, 256, 0, stream>>>(p);
        int gt_next = ((t + 1) % 10) < 5;
        dec_k<<<22, 256, 0, stream>>>(xseq, d_out, p, t, gt_next);
    }
}

// Round 3
// 11527.921 us; speedup vs baseline: 1.0929x; 1.0929x over previous
//
#include <hip/hip_runtime.h>

#define B_ 128
#define T_ 200
#define INF_ 175
#define INFP_ 192
#define H_ 1024
#define G4_ 4096
#define OUTF_ 175
#define BH3_ (3 * B_ * H_)

typedef __bf16 bf16x8 __attribute__((ext_vector_type(8)));
typedef float f32x4 __attribute__((ext_vector_type(4)));

// ---- persistent device state ----
__device__ __attribute__((aligned(16))) __bf16 g_Wih1p[G4_ * INFP_];
__device__ __attribute__((aligned(16))) __bf16 g_Whh1[G4_ * H_];
__device__ __attribute__((aligned(16))) __bf16 g_Wih2[G4_ * H_];
__device__ __attribute__((aligned(16))) __bf16 g_Whh2[G4_ * H_];
__device__ __attribute__((aligned(16))) __bf16 g_Wih3[G4_ * H_];
__device__ __attribute__((aligned(16))) __bf16 g_Whh3[G4_ * H_];
__device__ __attribute__((aligned(16))) __bf16 g_Wdec[OUTF_ * H_];
__device__ float g_bsum[3 * G4_];
__device__ float g_bdec[OUTF_];
__device__ __attribute__((aligned(16))) __bf16 g_h[2][BH3_];
__device__ float g_c[BH3_];
__device__ __attribute__((aligned(16))) __bf16 g_infp[B_ * INFP_];
__device__ int g_isf32;

__device__ __forceinline__ f32x4 mfma_bf16(bf16x8 a, bf16x8 b, f32x4 c) {
    return __builtin_amdgcn_mfma_f32_16x16x32_bf16(a, b, c, 0, 0, 0);
}
__device__ __forceinline__ bf16x8 ld8(const __bf16* p) {
    return *reinterpret_cast<const bf16x8*>(p);
}
__device__ __forceinline__ float sigm(float x) { return 1.f / (1.f + expf(-x)); }
__device__ __forceinline__ float rdf(const void* p, long i, int f32) {
    return f32 ? ((const float*)p)[i] : (float)((const __bf16*)p)[i];
}

// ---- dtype probe ----
__global__ void detect_k(const unsigned int* __restrict__ xw) {
    __shared__ int cnt;
    if (threadIdx.x == 0) cnt = 0;
    __syncthreads();
    unsigned int w = xw[threadIdx.x];
    int e = (w >> 7) & 0xFF;
    if (e >= 140) atomicAdd(&cnt, 1);
    __syncthreads();
    if (threadIdx.x == 0) g_isf32 = (cnt >= 16) ? 1 : 0;
}

// ---- prep ----
__global__ void prep_k(const void* Wih1, const void* Whh1, const void* Wih2,
                       const void* Whh2, const void* Wih3, const void* Whh3,
                       const void* Wdec, const void* bih1, const void* bhh1,
                       const void* bih2, const void* bhh2, const void* bih3,
                       const void* bhh3, const void* bdec, const void* xseq) {
    const int f = g_isf32;
    const int idx = blockIdx.x * 256 + threadIdx.x;
    const int stride = gridDim.x * 256;
    for (int i = idx; i < G4_ * INFP_; i += stride) {
        int n = i / INFP_, k = i - n * INFP_;
        g_Wih1p[i] = (k < INF_) ? (__bf16)rdf(Wih1, (long)n * INF_ + k, f) : (__bf16)0.f;
    }
    for (int i = idx; i < G4_ * H_; i += stride) {
        g_Whh1[i] = (__bf16)rdf(Whh1, i, f);
        g_Wih2[i] = (__bf16)rdf(Wih2, i, f);
        g_Whh2[i] = (__bf16)rdf(Whh2, i, f);
        g_Wih3[i] = (__bf16)rdf(Wih3, i, f);
        g_Whh3[i] = (__bf16)rdf(Whh3, i, f);
    }
    for (int i = idx; i < OUTF_ * H_; i += stride) g_Wdec[i] = (__bf16)rdf(Wdec, i, f);
    for (int i = idx; i < G4_; i += stride) {
        g_bsum[i]           = rdf(bih1, i, f) + rdf(bhh1, i, f);
        g_bsum[G4_ + i]     = rdf(bih2, i, f) + rdf(bhh2, i, f);
        g_bsum[2 * G4_ + i] = rdf(bih3, i, f) + rdf(bhh3, i, f);
    }
    for (int i = idx; i < OUTF_; i += stride) g_bdec[i] = rdf(bdec, i, f);
    for (int i = idx; i < 2 * BH3_; i += stride) (&g_h[0][0])[i] = (__bf16)0.f;
    for (int i = idx; i < BH3_; i += stride) g_c[i] = 0.f;
    for (int i = idx; i < B_ * INFP_; i += stride) {
        int b = i / INFP_, k = i - b * INFP_;
        g_infp[i] = (k < INF_) ? (__bf16)rdf(xseq, (long)b * (T_ * INF_) + k, f) : (__bf16)0.f;
    }
}

// 12-load bundle: 64 K-elements for 2 m-frags x 4 gates
struct Bun {
    bf16x8 a00, a01, a10, a11;
    bf16x8 b[4][2];
};

// ---- cells: 3 LSTM cells, one timestep; 192 blocks x 256 thr ----
// Software-pipelined depth-2 register prefetch, k-unroll 64.
__global__ __launch_bounds__(256) void cells_k(int p) {
    const int L = blockIdx.x >> 6;
    const int hc0 = (blockIdx.x & 63) << 4;
    const int lane = threadIdx.x & 63;
    const int wid = threadIdx.x >> 6;
    const int rlo = lane & 15;
    const int khi = lane >> 4;

    const __bf16* hin = g_h[p];

    const __bf16 *A0, *B0, *A1, *B1;
    int sA0, K0;
    if (L == 0)      { A0 = g_infp;          sA0 = INFP_; K0 = INFP_; B0 = g_Wih1p; A1 = hin;             B1 = g_Whh1; }
    else if (L == 1) { A0 = hin;             sA0 = H_;    K0 = H_;    B0 = g_Wih2;  A1 = hin + B_ * H_;   B1 = g_Whh2; }
    else             { A0 = hin + B_ * H_;   sA0 = H_;    K0 = H_;    B0 = g_Wih3;  A1 = hin + 2*B_*H_;   B1 = g_Whh3; }

    const int rm0 = wid * 32 + rlo;
    const int rm1 = rm0 + 16;
    const int wr = hc0 + rlo;        // W-row low bits (per gate: g*H_ + wr)
    const int n0 = K0 >> 6;          // 3 (L0) or 16
    const int n1 = H_ >> 6;          // 16
    const int total = n0 + n1;       // 19 or 32

    // precomputed lane base pointers
    const __bf16* a0b0 = A0 + rm0 * sA0 + khi * 8;
    const __bf16* a0b1 = A0 + rm1 * sA0 + khi * 8;
    const __bf16* a1b0 = A1 + rm0 * H_ + khi * 8;
    const __bf16* a1b1 = A1 + rm1 * H_ + khi * 8;

    f32x4 acc[2][4] = {};

    auto loadb = [&](Bun& x, int i) {
        const __bf16 *pa0, *pa1, *pb;
        int sB, k;
        if (i < n0) { k = i * 64;        pa0 = a0b0 + k; pa1 = a0b1 + k; pb = B0 + wr * K0 + k + khi * 8; sB = K0; }
        else        { k = (i - n0) * 64; pa0 = a1b0 + k; pa1 = a1b1 + k; pb = B1 + wr * H_ + k + khi * 8; sB = H_; }
        x.a00 = ld8(pa0); x.a01 = ld8(pa0 + 32);
        x.a10 = ld8(pa1); x.a11 = ld8(pa1 + 32);
#pragma unroll
        for (int g = 0; g < 4; ++g) {
            x.b[g][0] = ld8(pb + (long)g * H_ * sB);
            x.b[g][1] = ld8(pb + (long)g * H_ * sB + 32);
        }
    };
    auto mfma_bun = [&](Bun& x) {
#pragma unroll
        for (int g = 0; g < 4; ++g) {
            acc[0][g] = mfma_bf16(x.a00, x.b[g][0], acc[0][g]);
            acc[1][g] = mfma_bf16(x.a10, x.b[g][0], acc[1][g]);
            acc[0][g] = mfma_bf16(x.a01, x.b[g][1], acc[0][g]);
            acc[1][g] = mfma_bf16(x.a11, x.b[g][1], acc[1][g]);
        }
    };

    Bun u0, u1;
    loadb(u0, 0);
    loadb(u1, 1);
    for (int i = 0; i < total; i += 2) {
        mfma_bun(u0);
        if (i + 2 < total) loadb(u0, i + 2);
        if (i + 1 < total) {
            mfma_bun(u1);
            if (i + 3 < total) loadb(u1, i + 3);
        }
    }

    // epilogue: gates -> c,h (order i,f,g,o)
    float* cL = g_c + L * B_ * H_;
    __bf16* hL = g_h[p ^ 1] + L * B_ * H_;
    const float* bs = g_bsum + L * G4_;
    const int col = hc0 + rlo;
#pragma unroll
    for (int mi = 0; mi < 2; ++mi) {
#pragma unroll
        for (int j = 0; j < 4; ++j) {
            int row = wid * 32 + mi * 16 + khi * 4 + j;
            float gi = acc[mi][0][j] + bs[0 * H_ + col];
            float gf = acc[mi][1][j] + bs[1 * H_ + col];
            float gg = acc[mi][2][j] + bs[2 * H_ + col];
            float go = acc[mi][3][j] + bs[3 * H_ + col];
            float cn = sigm(gf) * cL[row * H_ + col] + sigm(gi) * tanhf(gg);
            cL[row * H_ + col] = cn;
            hL[row * H_ + col] = (__bf16)(sigm(go) * tanhf(cn));
        }
    }
}

// ---- decoder, same prefetch pattern; 22 blocks x 256 thr ----
struct Bun2 { bf16x8 a0, a1, b0, b1; };

__global__ __launch_bounds__(256) void dec_k(const void* __restrict__ xseq,
                                             void* __restrict__ dout,
                                             int p, int t, int gt_next) {
    const int nb = blockIdx.x % 11;
    const int mh = blockIdx.x / 11;
    const int lane = threadIdx.x & 63;
    const int wid = threadIdx.x >> 6;
    const int rlo = lane & 15, khi = lane >> 4;
    const int col = nb * 16 + rlo;
    const int colc = (col < OUTF_) ? col : (OUTF_ - 1);
    const int f = g_isf32;

    const __bf16* h2 = g_h[p ^ 1] + 2 * B_ * H_;
    const int rowA = mh * 64 + wid * 16 + rlo;
    const __bf16* pa = h2 + rowA * H_ + khi * 8;
    const __bf16* pb = g_Wdec + colc * H_ + khi * 8;

    f32x4 acc = {};
    auto loadb = [&](Bun2& x, int i) {
        int k = i * 64;
        x.a0 = ld8(pa + k); x.a1 = ld8(pa + k + 32);
        x.b0 = ld8(pb + k); x.b1 = ld8(pb + k + 32);
    };
    auto mfma_bun = [&](Bun2& x) {
        acc = mfma_bf16(x.a0, x.b0, acc);
        acc = mfma_bf16(x.a1, x.b1, acc);
    };

    const int total = H_ >> 6;  // 16
    Bun2 u0, u1;
    loadb(u0, 0);
    loadb(u1, 1);
    for (int i = 0; i < total; i += 2) {
        mfma_bun(u0);
        if (i + 2 < total) loadb(u0, i + 2);
        mfma_bun(u1);
        if (i + 3 < total) loadb(u1, i + 3);
    }

    if (col < OUTF_) {
        float bias = g_bdec[col];
#pragma unroll
        for (int j = 0; j < 4; ++j) {
            int row = mh * 64 + wid * 16 + khi * 4 + j;
            float ov = acc[j] + bias;
            long oidx = (long)row * (T_ * OUTF_) + (long)t * OUTF_ + col;
            if (f) ((float*)dout)[oidx] = ov;
            else   ((__bf16*)dout)[oidx] = (__bf16)ov;
            if (t + 1 < T_) {
                float nxt = gt_next ? rdf(xseq, (long)row * (T_ * INF_) + (long)(t + 1) * INF_ + col, f)
                                    : ov;
                g_infp[row * INFP_ + col] = (__bf16)nxt;
            }
        }
    }
}

extern "C" void kernel_launch(void* const* d_in, const int* in_sizes, int n_in,
                              void* d_out, int out_size, void* d_ws, size_t ws_size,
                              hipStream_t stream) {
    const void* xseq = d_in[0];
    detect_k<<<1, 256, 0, stream>>>((const unsigned int*)xseq);
    prep_k<<<2048, 256, 0, stream>>>(d_in[1], d_in[2], d_in[5], d_in[6], d_in[9],
                                     d_in[10], d_in[13], d_in[3], d_in[4], d_in[7],
                                     d_in[8], d_in[11], d_in[12], d_in[14], xseq);
    for (int t = 0; t < T_; ++t) {
        int p = t & 1;
        cells_k<<<192, 256, 0, stream>>>(p);
        int gt_next = ((t + 1) % 10) < 5;
        dec_k<<<22, 256, 0, stream>>>(xseq, d_out, p, t, gt_next);
    }
}